// Round 1
// 3365.307 us; speedup vs baseline: 1.1003x; 1.1003x over previous
//
#include <hip/hip_runtime.h>
#include <stdint.h>

typedef __attribute__((ext_vector_type(8))) short short8;
typedef __attribute__((ext_vector_type(4))) float floatx4;
typedef unsigned short ushort_t;

#define HDIM 128
#define K1   384
#define BM   256
#define BK   32
#define CAP  48
#define OVMAX 4096

__device__ __forceinline__ unsigned pack_bf16x2(float a, float b) {
  unsigned ua = __float_as_uint(a), ub = __float_as_uint(b);
  ua += 0x7FFFu + ((ua >> 16) & 1u);   // RNE
  ub += 0x7FFFu + ((ub >> 16) & 1u);
  return (ua >> 16) | (ub & 0xFFFF0000u);
}

__device__ __forceinline__ unsigned short bf16_rne(float f) {
  unsigned u = __float_as_uint(f);
  u += 0x7FFFu + ((u >> 16) & 1u);
  return (unsigned short)(u >> 16);
}

// Convert x -> bf16 copy, and W1/W2 (K-major) -> transposed bf16 Bt[n][k] for 3 MLPs.
__global__ void prep_kernel(const float* __restrict__ x,
    const float* __restrict__ w1a, const float* __restrict__ w2a,
    const float* __restrict__ w1b, const float* __restrict__ w2b,
    const float* __restrict__ w1c, const float* __restrict__ w2c,
    unsigned short* __restrict__ xb, unsigned short* __restrict__ bts, int Nx)
{
  int tid = blockIdx.x * 256 + threadIdx.x;
  if (tid < Nx) {                      // x: pack 2 floats -> 2 bf16
    float2 v = ((const float2*)x)[tid];
    ((unsigned*)xb)[tid] = pack_bf16x2(v.x, v.y);
    return;
  }
  int wI = tid - Nx;
  if (wI >= 3 * 65536) return;
  int m = wI >> 16;
  int r = wI & 65535;
  const float* W1 = (m == 0) ? w1a : (m == 1) ? w1b : w1c;
  const float* W2 = (m == 0) ? w2a : (m == 1) ? w2b : w2c;
  unsigned short* base = bts + (size_t)m * 65536;
  if (r < 49152) {                     // Bt1[n*384+k] = W1[k*128+n]
    int n = r / 384, k = r % 384;
    base[r] = bf16_rne(W1[(size_t)k * 128 + n]);
  } else {                             // Bt2[n*128+k] = W2[k*128+n]
    int r2 = r - 49152;
    int n = r2 >> 7, k = r2 & 127;
    base[49152 + r2] = bf16_rne(W2[(size_t)k * 128 + n]);
  }
}

// Bucket-build: per edge, append edge id to its receiver's bucket.
// Leaves cnt[] = degree. Overflow (deg > CAP, ~impossible) goes to a global list.
__global__ __launch_bounds__(256) void fill_kernel(
    const int* __restrict__ rm, int Em,
    const int* __restrict__ rw, int Ew,
    int* __restrict__ cnt_m, int* __restrict__ bucket_m,
    int* __restrict__ cnt_w, int* __restrict__ bucket_w,
    int* __restrict__ ovc,
    int* __restrict__ ove_m, int* __restrict__ ovr_m,
    int* __restrict__ ove_w, int* __restrict__ ovr_w)
{
  int tid = blockIdx.x * 256 + threadIdx.x;
  int e; const int* r; int* cnt; int* bucket; int* oc; int* oe; int* orr;
  if (tid < Em) {
    e = tid; r = rm; cnt = cnt_m; bucket = bucket_m;
    oc = ovc; oe = ove_m; orr = ovr_m;
  } else {
    e = tid - Em;
    if (e >= Ew) return;
    r = rw; cnt = cnt_w; bucket = bucket_w;
    oc = ovc + 1; oe = ove_w; orr = ovr_w;
  }
  int rr = r[e];
  int pos = atomicAdd(&cnt[rr], 1);
  if (pos < CAP) {
    bucket[(size_t)rr * CAP + pos] = e;
  } else {
    int o = atomicAdd(oc, 1);
    if (o < OVMAX) { oe[o] = e; orr[o] = rr; }
  }
}

// Gather-based segment sum: one wave per node, 64 lanes x 2 cols.
// em[e] is recovered as out[e] - attr[e] (out = attr + em was stored fp32).
// Writes agg directly in bf16 (the node GEMM consumes bf16 anyway).
__global__ __launch_bounds__(256) void gather_agg_kernel(
    const float* __restrict__ outp, const float* __restrict__ attr,
    const int* __restrict__ cnt, const int* __restrict__ bucket,
    const int* __restrict__ ovc, const int* __restrict__ ove, const int* __restrict__ ovr,
    unsigned short* __restrict__ agg, int Nn)
{
  int gw   = (int)((blockIdx.x * 256u + threadIdx.x) >> 6);
  int lane = threadIdx.x & 63;
  if (gw >= Nn) return;
  int deg  = cnt[gw];
  int degc = deg > CAP ? CAP : deg;
  const int* bk = bucket + (size_t)gw * CAP;
  int myE = (lane < degc) ? bk[lane] : 0;   // one coalesced read of the edge list
  float a0 = 0.f, a1 = 0.f;
  for (int i = 0; i < degc; ++i) {
    int e = __shfl(myE, i, 64);
    float2 o2 = *((const float2*)(outp + (size_t)e * HDIM) + lane);
    float2 r2 = *((const float2*)(attr + (size_t)e * HDIM) + lane);
    a0 += o2.x - r2.x;
    a1 += o2.y - r2.y;
  }
  if (deg > CAP) {                          // pathological fallback, normally dead
    int novf = *ovc;
    if (novf > OVMAX) novf = OVMAX;
    for (int i = 0; i < novf; ++i) {
      if (ovr[i] == gw) {
        int e = ove[i];
        float2 o2 = *((const float2*)(outp + (size_t)e * HDIM) + lane);
        float2 r2 = *((const float2*)(attr + (size_t)e * HDIM) + lane);
        a0 += o2.x - r2.x;
        a1 += o2.y - r2.y;
      }
    }
  }
  ((unsigned*)agg)[(size_t)gw * 64 + lane] = pack_bf16x2(a0, a1);
}

// MODE 0: edge block (gather x[s],x[r] via sidx/ridx; writes out = attr + em; NO scatter)
// MODE 1: node block (identity rows; ag1b/ag2b are agg_m/agg_w in bf16)
template <int MODE>
__global__ __launch_bounds__(256, 2) void mlp_ln_kernel(
    const unsigned short* __restrict__ xb,
    const unsigned short* __restrict__ ag1b,
    const unsigned short* __restrict__ ag2b,
    const float* __restrict__ eattr,
    const float* __restrict__ residf,
    const int* __restrict__ sidx, const int* __restrict__ ridx,
    const unsigned short* __restrict__ Bt1, const unsigned short* __restrict__ Bt2,
    const float* __restrict__ b1p, const float* __restrict__ b2p,
    const float* __restrict__ gp, const float* __restrict__ betap,
    float* __restrict__ outp, int E)
{
  // LDS: bufB (128 x 40 bf16) + union{ bufA 256 x 40 | bufH 128 x 136 } = 45 KB
  __shared__ unsigned short bufB[128 * 40];
  __shared__ unsigned short bufU[128 * 136];
  unsigned short* bufA = bufU;
  unsigned short* bufH = bufU;

  const int t = threadIdx.x;
  const int lane = t & 63, w = t >> 6;
  const int c = lane & 15, q = lane >> 4;
  const long long e0 = (long long)blockIdx.x * BM;

  // per-thread A-staging row (bf16 path: one row per thread)
  long long eg_t = e0 + t;
  if (eg_t > E - 1) eg_t = E - 1;
  const int rowc = (int)eg_t;
  int sIdx = 0, rIdx = 0;
  if (MODE == 0) { sIdx = sidx[rowc]; rIdx = ridx[rowc]; }

  int4 pa[8];
  int4 pb[2];

  auto loadB = [&](const unsigned short* Bt, int Kb, int kk) {
    int n = t >> 1;
#pragma unroll
    for (int i = 0; i < 2; ++i) {
      int sub = 2 * (t & 1) + i;
      pb[i] = *(const int4*)(Bt + (size_t)n * Kb + kk + sub * 8);
    }
  };
  auto storeB = [&]() {
    int n = t >> 1;
#pragma unroll
    for (int i = 0; i < 2; ++i) {
      int sub = 2 * (t & 1) + i;
      *(int4*)&bufB[n * 40 + sub * 8] = pb[i];
    }
  };
  auto loadA = [&](int kt) {
    int kk = kt * BK;
    int seg = kk >> 7;
    int ko = kk & 127;
    if (MODE == 1) {
      const unsigned short* base = (seg == 0) ? xb : (seg == 1) ? ag1b : ag2b;
      const int4* s4 = (const int4*)(base + (size_t)rowc * HDIM + ko);
      pa[0] = s4[0]; pa[1] = s4[1]; pa[2] = s4[2]; pa[3] = s4[3];
    } else if (seg <= 1) {
      const unsigned short* src = xb + (size_t)((seg == 0) ? sIdx : rIdx) * HDIM + ko;
      const int4* s4 = (const int4*)src;
      pa[0] = s4[0]; pa[1] = s4[1]; pa[2] = s4[2]; pa[3] = s4[3];
    } else {
      // MODE 0, seg 2: edge_attr fp32
#pragma unroll
      for (int j = 0; j < 4; ++j) {
        int P = j * 256 + t;
        int row = P >> 2, sub = P & 3;
        long long gr = e0 + row; if (gr > E - 1) gr = E - 1;
        const int4* s4 = (const int4*)(eattr + (size_t)gr * HDIM + ko + sub * 8);
        pa[2 * j]     = s4[0];
        pa[2 * j + 1] = s4[1];
      }
    }
  };
  auto storeA = [&](int kt) {
    int seg = (kt * BK) >> 7;
    if (MODE == 1 || seg <= 1) {
      int4* d = (int4*)&bufA[t * 40];
      d[0] = pa[0]; d[1] = pa[1]; d[2] = pa[2]; d[3] = pa[3];
    } else {
#pragma unroll
      for (int j = 0; j < 4; ++j) {
        int P = j * 256 + t;
        int row = P >> 2, sub = P & 3;
        int4 a0 = pa[2 * j], a1 = pa[2 * j + 1];
        int4 wv;
        wv.x = pack_bf16x2(__int_as_float(a0.x), __int_as_float(a0.y));
        wv.y = pack_bf16x2(__int_as_float(a0.z), __int_as_float(a0.w));
        wv.z = pack_bf16x2(__int_as_float(a1.x), __int_as_float(a1.y));
        wv.w = pack_bf16x2(__int_as_float(a1.z), __int_as_float(a1.w));
        *(int4*)&bufA[row * 40 + sub * 8] = wv;
      }
    }
  };

  // ---------------- GEMM1: [256 x 384] @ [384 x 128] ----------------
  floatx4 acc1[4][8];
#pragma unroll
  for (int mi = 0; mi < 4; ++mi)
#pragma unroll
    for (int nt = 0; nt < 8; ++nt) acc1[mi][nt] = (floatx4){0.f, 0.f, 0.f, 0.f};

  loadA(0); loadB(Bt1, K1, 0);
  for (int kt = 0; kt < 12; ++kt) {
    __syncthreads();
    storeA(kt); storeB();
    if (kt < 11) { loadA(kt + 1); loadB(Bt1, K1, (kt + 1) * BK); }
    else         { loadB(Bt2, 128, 0); }        // prefetch first GEMM2 B slice
    __syncthreads();
    short8 af[4];
#pragma unroll
    for (int mi = 0; mi < 4; ++mi)
      af[mi] = *(const short8*)&bufA[(w * 64 + mi * 16 + c) * 40 + q * 8];
#pragma unroll
    for (int nt = 0; nt < 8; ++nt) {
      short8 bf = *(const short8*)&bufB[(nt * 16 + c) * 40 + q * 8];
#pragma unroll
      for (int mi = 0; mi < 4; ++mi)
        acc1[mi][nt] = __builtin_amdgcn_mfma_f32_16x16x32_bf16(af[mi], bf, acc1[mi][nt], 0, 0, 0);
    }
  }

  // ---------------- GEMM2 + LN, two row-halves ----------------
  for (int h = 0; h < 2; ++h) {
    floatx4 acc2[2][8];
#pragma unroll
    for (int mip = 0; mip < 2; ++mip)
#pragma unroll
      for (int nt = 0; nt < 8; ++nt) acc2[mip][nt] = (floatx4){0.f, 0.f, 0.f, 0.f};

    for (int kt2 = 0; kt2 < 4; ++kt2) {
      __syncthreads();
      if (kt2 == 0) {
        // bias + ReLU + bf16, write h1 half into bufH (own-wave rows only)
        float b1v[8];
#pragma unroll
        for (int nt = 0; nt < 8; ++nt) b1v[nt] = b1p[nt * 16 + c];
#pragma unroll
        for (int mip = 0; mip < 2; ++mip) {
          int mi = 2 * h + mip;
#pragma unroll
          for (int nt = 0; nt < 8; ++nt) {
#pragma unroll
            for (int r = 0; r < 4; ++r) {
              float v = acc1[mi][nt][r] + b1v[nt];
              v = fmaxf(v, 0.0f);
              bufH[(w * 32 + mip * 16 + q * 4 + r) * 136 + nt * 16 + c] = bf16_rne(v);
            }
          }
        }
      }
      storeB();
      int u = h * 4 + kt2;
      if (u < 7) loadB(Bt2, 128, ((u + 1) & 3) * BK);
      __syncthreads();
      short8 af2[2];
#pragma unroll
      for (int mip = 0; mip < 2; ++mip)
        af2[mip] = *(const short8*)&bufH[(w * 32 + mip * 16 + c) * 136 + kt2 * 32 + q * 8];
#pragma unroll
      for (int nt = 0; nt < 8; ++nt) {
        short8 bf = *(const short8*)&bufB[(nt * 16 + c) * 40 + q * 8];
#pragma unroll
        for (int mip = 0; mip < 2; ++mip)
          acc2[mip][nt] = __builtin_amdgcn_mfma_f32_16x16x32_bf16(af2[mip], bf, acc2[mip][nt], 0, 0, 0);
      }
    }

    // epilogue: bias2 + LayerNorm + residual store (no scatter)
    float b2v[8], gv[8], bev[8];
#pragma unroll
    for (int nt = 0; nt < 8; ++nt) {
      b2v[nt] = b2p[nt * 16 + c];
      gv[nt]  = gp[nt * 16 + c];
      bev[nt] = betap[nt * 16 + c];
    }
#pragma unroll
    for (int mip = 0; mip < 2; ++mip) {
#pragma unroll
      for (int r = 0; r < 4; ++r) {
        float s1 = 0.f, s2 = 0.f;
#pragma unroll
        for (int nt = 0; nt < 8; ++nt) {
          float v = acc2[mip][nt][r] + b2v[nt];
          acc2[mip][nt][r] = v;
          s1 += v; s2 += v * v;
        }
#pragma unroll
        for (int m = 1; m < 16; m <<= 1) {
          s1 += __shfl_xor(s1, m, 64);
          s2 += __shfl_xor(s2, m, 64);
        }
        float mu  = s1 * (1.0f / 128.0f);
        float var = s2 * (1.0f / 128.0f) - mu * mu;
        float rs  = rsqrtf(var + 1e-5f);
        int blkrow = w * 64 + (2 * h + mip) * 16 + q * 4 + r;
        long long eg = e0 + blkrow;
        bool valid = eg < E;
#pragma unroll
        for (int nt = 0; nt < 8; ++nt) {
          int col = nt * 16 + c;
          float y = (acc2[mip][nt][r] - mu) * rs * gv[nt] + bev[nt];
          if (valid) {
            size_t o = (size_t)eg * HDIM + col;
            outp[o] = residf[o] + y;
          }
        }
      }
    }
  }
}

extern "C" void kernel_launch(void* const* d_in, const int* in_sizes, int n_in,
                              void* d_out, int out_size, void* d_ws, size_t ws_size,
                              hipStream_t stream) {
  (void)n_in; (void)out_size; (void)ws_size;
  const float* x  = (const float*)d_in[0];
  const float* ea = (const float*)d_in[1];
  const float* ew = (const float*)d_in[2];
  const float* P[18];
  for (int i = 0; i < 18; ++i) P[i] = (const float*)d_in[3 + i];
  const int* ei  = (const int*)d_in[21];
  const int* ewi = (const int*)d_in[22];
  const int N  = in_sizes[0] / 128;
  const int EM = in_sizes[21] / 2;
  const int EW = in_sizes[22] / 2;

  // ---- workspace layout (all bf16 / int; ~58 MB total) ----
  char* ws = (char*)d_ws;
  const size_t NB2 = (size_t)N * 128 * 2;
  unsigned short* xb     = (unsigned short*)ws;
  unsigned short* aggm_b = (unsigned short*)(ws + NB2);
  unsigned short* aggw_b = (unsigned short*)(ws + 2 * NB2);
  unsigned short* bts    = (unsigned short*)(ws + 3 * NB2);
  char* zr = ws + 3 * NB2 + 393216;
  int* cnt_m = (int*)zr;                       // N
  int* cnt_w = cnt_m + N;                      // N
  int* ovc   = cnt_w + N;                      // 2 (+pad to 64)
  int* ove_m = ovc + 64;                       // OVMAX
  int* ovr_m = ove_m + OVMAX;
  int* ove_w = ovr_m + OVMAX;
  int* ovr_w = ove_w + OVMAX;
  int* bucket_m = ovr_w + OVMAX;               // N*CAP
  int* bucket_w = bucket_m + (size_t)N * CAP;  // N*CAP

  // zero counters + overflow counts only
  hipMemsetAsync(cnt_m, 0, (size_t)(2 * N + 64) * 4, stream);

  int Nx = N * 64;
  int total = Nx + 3 * 65536;
  prep_kernel<<<(total + 255) / 256, 256, 0, stream>>>(
      x, P[0], P[2], P[6], P[8], P[12], P[14], xb, bts, Nx);

  // bucket build for both edge sets (receivers are ei+EM / ewi+EW)
  fill_kernel<<<(EM + EW + 255) / 256, 256, 0, stream>>>(
      ei + EM, EM, ewi + EW, EW,
      cnt_m, bucket_m, cnt_w, bucket_w,
      ovc, ove_m, ovr_m, ove_w, ovr_w);

  float* out0 = (float*)d_out;
  float* out1 = out0 + (size_t)N * 128;
  float* out2 = out1 + (size_t)EM * 128;

  unsigned short* Bt1_emb = bts;
  unsigned short* Bt2_emb = bts + 49152;
  unsigned short* Bt1_ewb = bts + 65536;
  unsigned short* Bt2_ewb = bts + 65536 + 49152;
  unsigned short* Bt1_nb  = bts + 131072;
  unsigned short* Bt2_nb  = bts + 131072 + 49152;

  // edge blocks: no scatter, just out = attr + em
  mlp_ln_kernel<0><<<(EM + BM - 1) / BM, 256, 0, stream>>>(
      xb, nullptr, nullptr, ea, ea, ei, ei + EM,
      Bt1_emb, Bt2_emb, P[1], P[3], P[4], P[5], out1, EM);
  mlp_ln_kernel<0><<<(EW + BM - 1) / BM, 256, 0, stream>>>(
      xb, nullptr, nullptr, ew, ew, ewi, ewi + EW,
      Bt1_ewb, Bt2_ewb, P[7], P[9], P[10], P[11], out2, EW);

  // gather-based segment sums -> bf16 agg
  gather_agg_kernel<<<(N * 64 + 255) / 256, 256, 0, stream>>>(
      out1, ea, cnt_m, bucket_m, ovc, ove_m, ovr_m, aggm_b, N);
  gather_agg_kernel<<<(N * 64 + 255) / 256, 256, 0, stream>>>(
      out2, ew, cnt_w, bucket_w, ovc + 1, ove_w, ovr_w, aggw_b, N);

  // node block: all-bf16 A segments
  mlp_ln_kernel<1><<<(N + BM - 1) / BM, 256, 0, stream>>>(
      xb, aggm_b, aggw_b, nullptr, x, nullptr, nullptr,
      Bt1_nb, Bt2_nb, P[13], P[15], P[16], P[17], out0, N);
}